// Round 5
// baseline (90.021 us; speedup 1.0000x reference)
//
#include <hip/hip_runtime.h>

// ReduceBoundingBoxes NMS over (5,80,80) fp32. Two kernels, no fences, no
// global atomics, no ws initialization. Cross-kernel ordering = stream order.
//   flat[i,c] = X[c*n+i], n = 6400
//   valid = f0 > 0.9 ; b5 = (f0, f1, f0+f2, f1+f3, f4)
//   stable sort valid desc by score; greedy NMS on b5[:,1:5]; row k =
//   kept ? b5_sorted[k] : 0.
//
// Exact identities:
//  1) R(i) = #{j: sj>si || (sj==si && j<i)} is a bijection [0,n)->[0,n)
//     (strict total order). For valid i it equals the NMS rank (outranking j
//     is itself valid); invalid i land exactly on [V,n) -> their rows are the
//     all-zero rows. Every row is covered exactly once -> NO memset.
//  2) Clamped-area==0 boxes have IoU exactly 0 with everything (monotone fp
//     rounding) -> greedy NMS == greedy NMS over the positive-area subset
//     (E[M] ~ 1 here).
//
// K1 (rankpart): partial rank counts into distinct slots part[c*n+i] --
//     register/float4 compares against L1-broadcast chunks (VALU-bound, the
//     R2-winning pattern). No init, no atomics.
// K2 (finish): groups blocks sum partials -> R(i) and write their rows,
//     SKIPPING positive-area rows; one extra block independently finds the
//     positive-area candidates, recomputes their ranks from part[], runs the
//     tiny greedy NMS in LDS, and exclusively writes those rows.
//     Disjoint row ownership -> zero cross-block communication.

#define CHUNK 400    // score elements per rank chunk (1600 B, 16B-aligned)
#define MAXM  1024   // positive-area capacity for the fix block

// ---- K1: partial rank counts ----
__global__ __launch_bounds__(256) void k_rankpart(
    const float* __restrict__ X, int* __restrict__ part, int n, int chunks) {
  const int c = blockIdx.x, g = blockIdx.y;
  const int i = g * 256 + threadIdx.x;
  const int c0 = c * CHUNK, cend = min(c0 + CHUNK, n);
  float si = (i < n) ? X[i] : -1.f;
  int gt = 0, eq = 0;
  const float4* X4 = (const float4*)(X + c0);
  const int nq = (cend - c0) >> 2;
  for (int q = 0; q < nq; ++q) {       // same addresses block-wide: L1 bcast
    float4 v = X4[q];
    gt += (v.x > si) + (v.y > si) + (v.z > si) + (v.w > si);
    eq += (v.x == si) + (v.y == si) + (v.z == si) + (v.w == si);
  }
  for (int j = c0 + (nq << 2); j < cend; ++j) {
    float sj = X[j];
    gt += (sj > si); eq += (sj == si);
  }
  if (i >= c0 && i < cend) eq -= 1;    // self-equality; exclude
  int partial = gt;
  if (__any(eq > 0)) {                 // true fp tie in this chunk: rare
    int eqlt = 0;
    for (int j = c0; j < cend; ++j)
      eqlt += (X[j] == si) && (j < i);
    partial = gt + eqlt;               // exact for every lane (0 if no tie)
  }
  if (i < n) part[c * n + i] = partial;
}

// ---- K2: row writes + independent fix block ----
__global__ __launch_bounds__(256) void k_finish(
    const float* __restrict__ X, const int* __restrict__ part,
    float* __restrict__ out, int n, int chunks, int groups) {
  const int t = threadIdx.x, b = blockIdx.x;

  if (b < groups) {
    // ---- row blocks: write every row except positive-area ones ----
    int i = b * 256 + t;
    if (i >= n) return;
    int r = 0;
    for (int c = 0; c < chunks; ++c) r += part[c * n + i];   // coalesced
    float s = X[i];
    float* row = out + (size_t)r * 5;
    if (s > 0.9f) {
      float f1 = X[n + i], f2 = X[2 * n + i], f3 = X[3 * n + i], f4 = X[4 * n + i];
      float c2 = s + f2, c3 = f1 + f3;
      // box = (f1, c2, c3, f4); reference-exact area arithmetic:
      float w = fmaxf(c3 - f1, 0.f);
      float h = fmaxf(f4 - c2, 0.f);
      if (w * h > 0.f) return;         // fix block exclusively owns this row
      row[0] = s; row[1] = f1; row[2] = c2; row[3] = c3; row[4] = f4;
    } else {
      row[0] = 0.f; row[1] = 0.f; row[2] = 0.f; row[3] = 0.f; row[4] = 0.f;
    }
    return;
  }

  // ---- fix block: positive-area candidates only (E[M] ~ 1) ----
  __shared__ int   mcnt, sflag;
  __shared__ int   cand[MAXM];
  __shared__ int   srnk[MAXM];
  __shared__ int   ornk[MAXM];
  __shared__ float obox[MAXM][5];
  __shared__ float oarea[MAXM];
  __shared__ int   okeep[MAXM];
  if (t == 0) mcnt = 0;
  __syncthreads();
  for (int i = t; i < n; i += 256) {
    float s = X[i];
    if (s > 0.9f) {
      float f1 = X[n + i], f2 = X[2 * n + i], f3 = X[3 * n + i], f4 = X[4 * n + i];
      float c2 = s + f2, c3 = f1 + f3;
      float w = fmaxf(c3 - f1, 0.f);
      float h = fmaxf(f4 - c2, 0.f);   // identical fp to row blocks' test
      if (w * h > 0.f) {
        int p = atomicAdd(&mcnt, 1);   // LDS-local only
        if (p < MAXM) cand[p] = i;
      }
    }
  }
  __syncthreads();
  const int M = min(mcnt, MAXM);
  if (M == 0) return;
  for (int e = t; e < M; e += 256) {   // ranks from the same partials
    int i = cand[e];
    int r = 0;
    for (int c = 0; c < chunks; ++c) r += part[c * n + i];
    srnk[e] = r;
  }
  __syncthreads();
  for (int e = t; e < M; e += 256) {   // scatter into rank order (distinct)
    int r = srnk[e], i = cand[e];
    int pos = 0;
    for (int m = 0; m < M; ++m) pos += (srnk[m] < r);
    float s = X[i], f1 = X[n + i], f2 = X[2 * n + i], f3 = X[3 * n + i], f4 = X[4 * n + i];
    float c2 = s + f2, c3 = f1 + f3;
    ornk[pos] = r;
    obox[pos][0] = s; obox[pos][1] = f1; obox[pos][2] = c2;
    obox[pos][3] = c3; obox[pos][4] = f4;
    oarea[pos] = fmaxf(c3 - f1, 0.f) * fmaxf(f4 - c2, 0.f);
    okeep[pos] = 1;
  }
  __syncthreads();
  // greedy NMS, reference-exact fp; box coords = obox[][1..4]
  for (int i = 1; i < M; ++i) {
    if (t == 0) sflag = 0;
    __syncthreads();
    if (t < i && okeep[t]) {
      float ltx = fmaxf(obox[t][1], obox[i][1]);
      float lty = fmaxf(obox[t][2], obox[i][2]);
      float rbx = fminf(obox[t][3], obox[i][3]);
      float rby = fminf(obox[t][4], obox[i][4]);
      float w = fmaxf(rbx - ltx, 0.f);
      float h = fmaxf(rby - lty, 0.f);
      float inter = w * h;
      float uni = oarea[t] + oarea[i] - inter;
      if (inter / fmaxf(uni, 1e-9f) > 0.5f) sflag = 1;
    }
    __syncthreads();
    if (t == 0 && sflag) okeep[i] = 0;
    __syncthreads();
  }
  for (int e = t; e < M; e += 256) {   // exclusively-owned rows
    float* row = out + (size_t)ornk[e] * 5;
    if (okeep[e]) {
      row[0] = obox[e][0]; row[1] = obox[e][1]; row[2] = obox[e][2];
      row[3] = obox[e][3]; row[4] = obox[e][4];
    } else {
      row[0] = 0.f; row[1] = 0.f; row[2] = 0.f; row[3] = 0.f; row[4] = 0.f;
    }
  }
}

// ---- Fallback: single-block kernel (only if ws too small; never here) ----
#define FB_NTH  1024
#define FB_MAXV 2048
#define FB_MAXM 256
__global__ __launch_bounds__(FB_NTH, 1) void nms_fallback(
    const float* __restrict__ X, float* __restrict__ out, int n, int out_n) {
  __shared__ float cscore[FB_MAXV];
  __shared__ unsigned int cidx[FB_MAXV];
  __shared__ int s_vcount, s_mcount, sflag;
  __shared__ int srank[FB_MAXM];
  __shared__ float sbox[FB_MAXM][4];
  __shared__ float sarea[FB_MAXM];
  __shared__ int skeep[FB_MAXM];
  __shared__ int prank[FB_MAXM];
  __shared__ float pbox[FB_MAXM][4];
  __shared__ float parea[FB_MAXM];
  const int t = threadIdx.x;
  if (t == 0) { s_vcount = 0; s_mcount = 0; }
  float4* out4 = (float4*)out;
  int n4 = out_n >> 2;
  for (int i = t; i < n4; i += FB_NTH) out4[i] = make_float4(0.f, 0.f, 0.f, 0.f);
  for (int i = (n4 << 2) + t; i < out_n; i += FB_NTH) out[i] = 0.f;
  __syncthreads();
  for (int i = t; i < n; i += FB_NTH) {
    float s = X[i];
    if (s > 0.9f) {
      int p = atomicAdd(&s_vcount, 1);
      if (p < FB_MAXV) { cscore[p] = s; cidx[p] = (unsigned int)i; }
    }
  }
  __syncthreads();
  const int V = min(s_vcount, FB_MAXV);
  for (int e = t; e < V; e += FB_NTH) {
    float s = cscore[e];
    unsigned int idx = cidx[e];
    int rank = 0;
    for (int m = 0; m < V; ++m) {
      float sm = cscore[m];
      rank += (sm > s) || (sm == s && cidx[m] < idx);
    }
    float f1 = X[n + idx], f2 = X[2 * n + idx], f3 = X[3 * n + idx], f4 = X[4 * n + idx];
    float c2 = s + f2, c3 = f1 + f3;
    float* row = out + (size_t)rank * 5;
    row[0] = s; row[1] = f1; row[2] = c2; row[3] = c3; row[4] = f4;
    float w = fmaxf(c3 - f1, 0.f), h = fmaxf(f4 - c2, 0.f);
    float area = w * h;
    if (area > 0.f) {
      int p = atomicAdd(&s_mcount, 1);
      if (p < FB_MAXM) {
        prank[p] = rank;
        pbox[p][0] = f1; pbox[p][1] = c2; pbox[p][2] = c3; pbox[p][3] = f4;
        parea[p] = area;
      }
    }
  }
  __syncthreads();
  const int M = min(s_mcount, FB_MAXM);
  for (int e = t; e < M; e += FB_NTH) {
    int r = prank[e];
    int pos = 0;
    for (int m = 0; m < M; ++m) pos += (prank[m] < r);
    srank[pos] = r;
    sbox[pos][0] = pbox[e][0]; sbox[pos][1] = pbox[e][1];
    sbox[pos][2] = pbox[e][2]; sbox[pos][3] = pbox[e][3];
    sarea[pos] = parea[e];
    skeep[pos] = 1;
  }
  __syncthreads();
  for (int s = 1; s < M; ++s) {
    if (t == 0) sflag = 0;
    __syncthreads();
    if (t < s && skeep[t]) {
      float ltx = fmaxf(sbox[t][0], sbox[s][0]);
      float lty = fmaxf(sbox[t][1], sbox[s][1]);
      float rbx = fminf(sbox[t][2], sbox[s][2]);
      float rby = fminf(sbox[t][3], sbox[s][3]);
      float w = fmaxf(rbx - ltx, 0.f), h = fmaxf(rby - lty, 0.f);
      float inter = w * h;
      float uni = sarea[t] + sarea[s] - inter;
      if (inter / fmaxf(uni, 1e-9f) > 0.5f) sflag = 1;
    }
    __syncthreads();
    if (t == 0 && sflag) skeep[s] = 0;
    __syncthreads();
  }
  for (int e = t; e < M; e += FB_NTH) {
    if (!skeep[e]) {
      float* row = out + (size_t)srank[e] * 5;
      row[0] = 0.f; row[1] = 0.f; row[2] = 0.f; row[3] = 0.f; row[4] = 0.f;
    }
  }
}

extern "C" void kernel_launch(void* const* d_in, const int* in_sizes, int n_in,
                              void* d_out, int out_size, void* d_ws, size_t ws_size,
                              hipStream_t stream) {
  const float* X = (const float*)d_in[0];
  float* out = (float*)d_out;
  int n = in_sizes[0] / 5;                  // 6400
  int groups = (n + 255) / 256;             // 25
  int chunks = (n + CHUNK - 1) / CHUNK;     // 16
  size_t need = (size_t)chunks * n * sizeof(int);   // ~410 KB
  if (ws_size >= need) {
    int* part = (int*)d_ws;
    hipLaunchKernelGGL(k_rankpart, dim3(chunks, groups), dim3(256), 0, stream,
                       X, part, n, chunks);
    hipLaunchKernelGGL(k_finish, dim3(groups + 1), dim3(256), 0, stream,
                       X, part, out, n, chunks, groups);
  } else {
    hipLaunchKernelGGL(nms_fallback, dim3(1), dim3(FB_NTH), 0, stream, X, out, n, out_size);
  }
}

// Round 6
// 76.817 us; speedup vs baseline: 1.1719x; 1.1719x over previous
//
#include <hip/hip_runtime.h>

// ReduceBoundingBoxes NMS over (5,80,80) fp32 — R2 structure (best measured:
// 65.4 us) with the 1-block NMS kernel fused into the row kernel via an
// independent fix block (disjoint row ownership; no fences, no flags).
//   flat[i,c] = X[c*n+i], n = 6400
//   valid = f0 > 0.9 ; b5 = (f0, f1, f0+f2, f1+f3, f4)
//   stable sort valid desc by score; greedy NMS on b5[:,1:5]; row k =
//   kept ? b5_sorted[k] : 0.
//
// Exact identities:
//  1) For valid i (s>0.9), rank = #{j: sj>si || (sj==si && j<i)} over ALL j
//     equals the NMS rank (any outranking j is itself valid). Ties of a
//     valid score only occur with valid j. Only valid ranks are ever used.
//  2) Clamped-area==0 boxes have IoU exactly 0 with everything (monotone fp
//     rounding) -> greedy NMS == greedy NMS over the positive-area subset
//     (E[M] ~ 1 for this input). Suppressed & invalid rows stay at the
//     memset zeros -> fix block only writes KEPT positive-area rows.
//
// K1 k_zero:  coalesced float4 memset of out (128 KB) + ranks (25.6 KB).
// K2 k_rank:  partial rank counts, 1-wave blocks, register/float4 compares
//             vs L1-broadcast chunks; atomicAdd gated to valid lanes.
// K3 k_rows:  blocks 0..24 write valid zero-area rows (scattered, ~640);
//             block 25 independently finds positive-area candidates, reads
//             their ranks, runs greedy NMS in LDS, writes kept rows.

#define CHUNK 200    // score elements per rank chunk
#define MAXM  1024   // positive-area capacity for the fix block

// ---- K1: zero output + ranks ----
__global__ __launch_bounds__(256) void k_zero(
    float* __restrict__ out, int out_n, int* __restrict__ ranks, int n) {
  int tid = blockIdx.x * blockDim.x + threadIdx.x;
  int nt = gridDim.x * blockDim.x;
  float4* o4 = (float4*)out;
  int n4 = out_n >> 2;
  for (int i = tid; i < n4; i += nt) o4[i] = make_float4(0.f, 0.f, 0.f, 0.f);
  for (int i = (n4 << 2) + tid; i < out_n; i += nt) out[i] = 0.f;
  int4* r4 = (int4*)ranks;
  int rn4 = n >> 2;
  for (int i = tid; i < rn4; i += nt) r4[i] = make_int4(0, 0, 0, 0);
  for (int i = (rn4 << 2) + tid; i < n; i += nt) ranks[i] = 0;
}

// ---- K2: partial rank counts (R2-identical) ----
__global__ __launch_bounds__(64) void k_rank(const float* __restrict__ X,
                                             int* __restrict__ ranks, int n) {
  int i = blockIdx.x * 64 + threadIdx.x;
  int c0 = blockIdx.y * CHUNK;
  int cend = min(c0 + CHUNK, n);
  float si = (i < n) ? X[i] : -1.f;
  bool valid = (i < n) && (si > 0.9f);
  int gt = 0, eq = 0;
  const float4* X4 = (const float4*)(X + c0);
  int nq = (cend - c0) >> 2;
  for (int q = 0; q < nq; ++q) {       // same addresses wave-wide: L1 bcast
    float4 v = X4[q];
    gt += (v.x > si) + (v.y > si) + (v.z > si) + (v.w > si);
    eq += (v.x == si) + (v.y == si) + (v.z == si) + (v.w == si);
  }
  for (int j = c0 + (nq << 2); j < cend; ++j) {
    float sj = X[j];
    gt += (sj > si); eq += (sj == si);
  }
  if (i >= c0 && i < cend) eq -= 1;    // self-equality; exclude
  int partial = gt;
  if (__any(valid && eq > 0)) {        // true fp tie vs a valid lane: rare
    int eqlt = 0;
    for (int j = c0; j < cend; ++j)
      eqlt += (X[j] == si) && (j < i);
    partial = gt + eqlt;               // exact for every lane (0 if no tie)
  }
  if (valid && partial > 0) atomicAdd(&ranks[i], partial);
}

// ---- K3: row writes + independent fix block (disjoint row ownership) ----
__global__ __launch_bounds__(256) void k_rows(
    const float* __restrict__ X, const int* __restrict__ ranks,
    float* __restrict__ out, int n, int groups) {
  const int t = threadIdx.x, b = blockIdx.x;

  if (b < groups) {
    // ---- row blocks: valid zero-area rows only (~640 scattered writes) ----
    int i = b * 256 + t;
    if (i >= n) return;
    float s = X[i];
    if (!(s > 0.9f)) return;                       // invalid: row stays zero
    float f1 = X[n + i], f2 = X[2 * n + i], f3 = X[3 * n + i], f4 = X[4 * n + i];
    float c2 = s + f2, c3 = f1 + f3;
    // box = (f1, c2, c3, f4); reference-exact area arithmetic:
    float w = fmaxf(c3 - f1, 0.f);
    float h = fmaxf(f4 - c2, 0.f);
    if (w * h > 0.f) return;                       // fix block owns this row
    float* row = out + (size_t)ranks[i] * 5;
    row[0] = s; row[1] = f1; row[2] = c2; row[3] = c3; row[4] = f4;
    return;
  }

  // ---- fix block: positive-area candidates (E[M] ~ 1) ----
  __shared__ int   mcnt, sflag;
  __shared__ int   cand[MAXM];
  __shared__ int   srnk[MAXM];
  __shared__ int   ornk[MAXM];
  __shared__ float obox[MAXM][5];
  __shared__ float oarea[MAXM];
  __shared__ int   okeep[MAXM];
  if (t == 0) mcnt = 0;
  __syncthreads();
  for (int i = t; i < n; i += 256) {
    float s = X[i];
    if (s > 0.9f) {
      float f1 = X[n + i], f2 = X[2 * n + i], f3 = X[3 * n + i], f4 = X[4 * n + i];
      float c2 = s + f2, c3 = f1 + f3;
      float w = fmaxf(c3 - f1, 0.f);
      float h = fmaxf(f4 - c2, 0.f);   // identical fp to row blocks' test
      if (w * h > 0.f) {
        int p = atomicAdd(&mcnt, 1);   // LDS-local
        if (p < MAXM) cand[p] = i;
      }
    }
  }
  __syncthreads();
  const int M = min(mcnt, MAXM);
  if (M == 0) return;
  for (int e = t; e < M; e += 256) srnk[e] = ranks[cand[e]];
  __syncthreads();
  for (int e = t; e < M; e += 256) {   // scatter into rank order (distinct)
    int r = srnk[e], i = cand[e];
    int pos = 0;
    for (int m = 0; m < M; ++m) pos += (srnk[m] < r);
    float s = X[i], f1 = X[n + i], f2 = X[2 * n + i], f3 = X[3 * n + i], f4 = X[4 * n + i];
    float c2 = s + f2, c3 = f1 + f3;
    ornk[pos] = r;
    obox[pos][0] = s; obox[pos][1] = f1; obox[pos][2] = c2;
    obox[pos][3] = c3; obox[pos][4] = f4;
    oarea[pos] = fmaxf(c3 - f1, 0.f) * fmaxf(f4 - c2, 0.f);
    okeep[pos] = 1;
  }
  __syncthreads();
  // greedy NMS, reference-exact fp; box coords = obox[][1..4]
  for (int i = 1; i < M; ++i) {
    if (t == 0) sflag = 0;
    __syncthreads();
    if (t < i && okeep[t]) {
      float ltx = fmaxf(obox[t][1], obox[i][1]);
      float lty = fmaxf(obox[t][2], obox[i][2]);
      float rbx = fminf(obox[t][3], obox[i][3]);
      float rby = fminf(obox[t][4], obox[i][4]);
      float w = fmaxf(rbx - ltx, 0.f);
      float h = fmaxf(rby - lty, 0.f);
      float inter = w * h;
      float uni = oarea[t] + oarea[i] - inter;
      if (inter / fmaxf(uni, 1e-9f) > 0.5f) sflag = 1;
    }
    __syncthreads();
    if (t == 0 && sflag) okeep[i] = 0;
    __syncthreads();
  }
  for (int e = t; e < M; e += 256) {   // kept rows only; suppressed stay zero
    if (okeep[e]) {
      float* row = out + (size_t)ornk[e] * 5;
      row[0] = obox[e][0]; row[1] = obox[e][1]; row[2] = obox[e][2];
      row[3] = obox[e][3]; row[4] = obox[e][4];
    }
  }
}

// ---- Fallback: single-block kernel (only if ws too small; never here) ----
#define FB_NTH  1024
#define FB_MAXV 2048
#define FB_MAXM 256
__global__ __launch_bounds__(FB_NTH, 1) void nms_fallback(
    const float* __restrict__ X, float* __restrict__ out, int n, int out_n) {
  __shared__ float cscore[FB_MAXV];
  __shared__ unsigned int cidx[FB_MAXV];
  __shared__ int s_vcount, s_mcount, sflag;
  __shared__ int srank[FB_MAXM];
  __shared__ float sbox[FB_MAXM][4];
  __shared__ float sarea[FB_MAXM];
  __shared__ int skeep[FB_MAXM];
  __shared__ int prank[FB_MAXM];
  __shared__ float pbox[FB_MAXM][4];
  __shared__ float parea[FB_MAXM];
  const int t = threadIdx.x;
  if (t == 0) { s_vcount = 0; s_mcount = 0; }
  float4* out4 = (float4*)out;
  int n4 = out_n >> 2;
  for (int i = t; i < n4; i += FB_NTH) out4[i] = make_float4(0.f, 0.f, 0.f, 0.f);
  for (int i = (n4 << 2) + t; i < out_n; i += FB_NTH) out[i] = 0.f;
  __syncthreads();
  for (int i = t; i < n; i += FB_NTH) {
    float s = X[i];
    if (s > 0.9f) {
      int p = atomicAdd(&s_vcount, 1);
      if (p < FB_MAXV) { cscore[p] = s; cidx[p] = (unsigned int)i; }
    }
  }
  __syncthreads();
  const int V = min(s_vcount, FB_MAXV);
  for (int e = t; e < V; e += FB_NTH) {
    float s = cscore[e];
    unsigned int idx = cidx[e];
    int rank = 0;
    for (int m = 0; m < V; ++m) {
      float sm = cscore[m];
      rank += (sm > s) || (sm == s && cidx[m] < idx);
    }
    float f1 = X[n + idx], f2 = X[2 * n + idx], f3 = X[3 * n + idx], f4 = X[4 * n + idx];
    float c2 = s + f2, c3 = f1 + f3;
    float* row = out + (size_t)rank * 5;
    row[0] = s; row[1] = f1; row[2] = c2; row[3] = c3; row[4] = f4;
    float w = fmaxf(c3 - f1, 0.f), h = fmaxf(f4 - c2, 0.f);
    float area = w * h;
    if (area > 0.f) {
      int p = atomicAdd(&s_mcount, 1);
      if (p < FB_MAXM) {
        prank[p] = rank;
        pbox[p][0] = f1; pbox[p][1] = c2; pbox[p][2] = c3; pbox[p][3] = f4;
        parea[p] = area;
      }
    }
  }
  __syncthreads();
  const int M = min(s_mcount, FB_MAXM);
  for (int e = t; e < M; e += FB_NTH) {
    int r = prank[e];
    int pos = 0;
    for (int m = 0; m < M; ++m) pos += (prank[m] < r);
    srank[pos] = r;
    sbox[pos][0] = pbox[e][0]; sbox[pos][1] = pbox[e][1];
    sbox[pos][2] = pbox[e][2]; sbox[pos][3] = pbox[e][3];
    sarea[pos] = parea[e];
    skeep[pos] = 1;
  }
  __syncthreads();
  for (int s = 1; s < M; ++s) {
    if (t == 0) sflag = 0;
    __syncthreads();
    if (t < s && skeep[t]) {
      float ltx = fmaxf(sbox[t][0], sbox[s][0]);
      float lty = fmaxf(sbox[t][1], sbox[s][1]);
      float rbx = fminf(sbox[t][2], sbox[s][2]);
      float rby = fminf(sbox[t][3], sbox[s][3]);
      float w = fmaxf(rbx - ltx, 0.f), h = fmaxf(rby - lty, 0.f);
      float inter = w * h;
      float uni = sarea[t] + sarea[s] - inter;
      if (inter / fmaxf(uni, 1e-9f) > 0.5f) sflag = 1;
    }
    __syncthreads();
    if (t == 0 && sflag) skeep[s] = 0;
    __syncthreads();
  }
  for (int e = t; e < M; e += FB_NTH) {
    if (!skeep[e]) {
      float* row = out + (size_t)srank[e] * 5;
      row[0] = 0.f; row[1] = 0.f; row[2] = 0.f; row[3] = 0.f; row[4] = 0.f;
    }
  }
}

extern "C" void kernel_launch(void* const* d_in, const int* in_sizes, int n_in,
                              void* d_out, int out_size, void* d_ws, size_t ws_size,
                              hipStream_t stream) {
  const float* X = (const float*)d_in[0];
  float* out = (float*)d_out;
  int n = in_sizes[0] / 5;                  // 6400
  int g64 = (n + 63) / 64;                  // 100
  int chunks = (n + CHUNK - 1) / CHUNK;     // 32
  int groups = (n + 255) / 256;             // 25
  size_t need = (size_t)n * sizeof(int);
  if (ws_size >= need) {
    int* ranks = (int*)d_ws;
    hipLaunchKernelGGL(k_zero, dim3(80), dim3(256), 0, stream, out, out_size, ranks, n);
    hipLaunchKernelGGL(k_rank, dim3(g64, chunks), dim3(64), 0, stream, X, ranks, n);
    hipLaunchKernelGGL(k_rows, dim3(groups + 1), dim3(256), 0, stream, X, ranks, out, n, groups);
  } else {
    hipLaunchKernelGGL(nms_fallback, dim3(1), dim3(FB_NTH), 0, stream, X, out, n, out_size);
  }
}

// Round 7
// 71.407 us; speedup vs baseline: 1.2607x; 1.0758x over previous
//
#include <hip/hip_runtime.h>

// ReduceBoundingBoxes NMS over (5,80,80) fp32 — R2 structure (best measured:
// 65.4 us) with k_zero folded away: rank partials go to distinct ws slots
// (no init, no atomics) and `out` is zeroed by extra blocks of the SAME
// first launch. K2/K3 are R2's k_rows/k_nms with ranks[i] -> sum of parts.
//   flat[i,c] = X[c*n+i], n = 6400
//   valid = f0 > 0.9 ; b5 = (f0, f1, f0+f2, f1+f3, f4)
//   stable sort valid desc by score; greedy NMS on b5[:,1:5]; row k =
//   kept ? b5_sorted[k] : 0.
//
// Exact identities:
//  1) For valid i (s>0.9), rank = #{j: sj>si || (sj==si && j<i)} over ALL j
//     equals the NMS rank (any outranking j is itself valid; ties of a valid
//     score are with valid j). Valid ranks are a bijection onto [0,V) ->
//     rows [V,n) stay at the K1 zeros.
//  2) Clamped-area==0 boxes have IoU exactly 0 with everything (monotone fp
//     rounding) -> greedy NMS == greedy NMS over the positive-area subset
//     (E[M] ~ 1 here). K3 only has to zero SUPPRESSED rows.
//
// K1 k_prep: blocks [0, chunks*groups): partial rank counts into
//            part[c*n+i] (plain stores); blocks [chunks*groups, +32):
//            float4-zero `out` + zero the list counter.
// K2 k_rows: valid threads sum 32 partials -> rank, write b5 row, append
//            positive-area entries to list (1 global atomic, ~M ops).
// K3 k_nms:  1 block: sort list by rank, greedy NMS, zero suppressed rows.

#define CHUNK 200    // score elements per rank chunk
#define ZB    32     // zero-blocks appended to K1
#define MAXM  256    // positive-area list capacity (E[M] ~ 1)

// ---- K1: rank partials + output zeroing, one launch ----
__global__ __launch_bounds__(256) void k_prep(
    const float* __restrict__ X, int* __restrict__ part, int* __restrict__ cnt,
    float* __restrict__ out, int out_n, int n, int chunks, int groups) {
  const int b = blockIdx.x, t = threadIdx.x;
  const int nrank = chunks * groups;

  if (b >= nrank) {                    // ---- zero blocks ----
    int b2 = b - nrank;
    int tid = b2 * 256 + t;
    float4* o4 = (float4*)out;
    int n4 = out_n >> 2;
    for (int i = tid; i < n4; i += ZB * 256)
      o4[i] = make_float4(0.f, 0.f, 0.f, 0.f);
    for (int i = (n4 << 2) + tid; i < out_n; i += ZB * 256)
      out[i] = 0.f;
    if (b2 == 0 && t < 8) cnt[t] = 0;
    return;
  }

  // ---- rank-partial blocks (R2's compare loop, 256-thr, c-major) ----
  const int c = b % chunks, g = b / chunks;
  const int i = g * 256 + t;
  const int c0 = c * CHUNK, cend = min(c0 + CHUNK, n);
  float si = (i < n) ? X[i] : -1.f;
  bool valid = (i < n) && (si > 0.9f);
  int gt = 0, eq = 0;
  const float4* X4 = (const float4*)(X + c0);
  const int nq = (cend - c0) >> 2;
  for (int q = 0; q < nq; ++q) {       // same addresses block-wide: L1 bcast
    float4 v = X4[q];
    gt += (v.x > si) + (v.y > si) + (v.z > si) + (v.w > si);
    eq += (v.x == si) + (v.y == si) + (v.z == si) + (v.w == si);
  }
  for (int j = c0 + (nq << 2); j < cend; ++j) {
    float sj = X[j];
    gt += (sj > si); eq += (sj == si);
  }
  if (i >= c0 && i < cend) eq -= 1;    // self-equality; exclude
  int partial = gt;
  if (__any(valid && eq > 0)) {        // true fp tie vs a valid lane: rare
    int eqlt = 0;
    for (int j = c0; j < cend; ++j)
      eqlt += (X[j] == si) && (j < i);
    partial = gt + eqlt;               // exact for every lane (0 if no tie)
  }
  if (i < n) part[c * n + i] = partial;
}

// ---- K2: write b5 rows at final rank; collect positive-area boxes ----
__global__ __launch_bounds__(256) void k_rows(
    const float* __restrict__ X, const int* __restrict__ part,
    float* __restrict__ out, float* __restrict__ list,
    int* __restrict__ cnt, int n, int chunks) {
  int i = blockIdx.x * 256 + threadIdx.x;
  if (i >= n) return;
  float s = X[i];
  if (!(s > 0.9f)) return;             // invalid: row stays at K1 zeros
  int r = 0;
  for (int c = 0; c < chunks; ++c) r += part[c * n + i];   // coalesced per c
  float f1 = X[n + i], f2 = X[2 * n + i], f3 = X[3 * n + i], f4 = X[4 * n + i];
  float c2 = s + f2, c3 = f1 + f3;
  float* row = out + (size_t)r * 5;
  row[0] = s; row[1] = f1; row[2] = c2; row[3] = c3; row[4] = f4;
  // box = (f1, c2, c3, f4); reference-exact area arithmetic:
  float w = fmaxf(c3 - f1, 0.f);
  float h = fmaxf(f4 - c2, 0.f);
  float area = w * h;
  if (area > 0.f) {
    int p = atomicAdd(cnt, 1);
    if (p < MAXM) {
      float* e = list + (size_t)p * 6;
      e[0] = __int_as_float(r);
      e[1] = f1; e[2] = c2; e[3] = c3; e[4] = f4; e[5] = area;
    }
  }
}

// ---- K3: greedy NMS over positive-area boxes; zero suppressed rows ----
__global__ __launch_bounds__(256) void k_nms(const float* __restrict__ list,
                                             const int* __restrict__ cnt,
                                             float* __restrict__ out) {
  __shared__ int   srank[MAXM];
  __shared__ float sbox[MAXM][4];
  __shared__ float sarea[MAXM];
  __shared__ int   skeep[MAXM];
  __shared__ int   sflag;
  int t = threadIdx.x;
  int M = *cnt;
  if (M > MAXM) M = MAXM;
  for (int e = t; e < M; e += 256) {   // rank-sort (ranks distinct)
    int r = __float_as_int(list[e * 6 + 0]);
    int pos = 0;
    for (int m = 0; m < M; ++m)
      pos += (__float_as_int(list[m * 6 + 0]) < r);
    srank[pos] = r;
    sbox[pos][0] = list[e * 6 + 1];
    sbox[pos][1] = list[e * 6 + 2];
    sbox[pos][2] = list[e * 6 + 3];
    sbox[pos][3] = list[e * 6 + 4];
    sarea[pos]   = list[e * 6 + 5];
    skeep[pos] = 1;
  }
  __syncthreads();
  for (int i = 1; i < M; ++i) {        // greedy NMS, reference-exact fp
    if (t == 0) sflag = 0;
    __syncthreads();
    if (t < i && skeep[t]) {
      float ltx = fmaxf(sbox[t][0], sbox[i][0]);
      float lty = fmaxf(sbox[t][1], sbox[i][1]);
      float rbx = fminf(sbox[t][2], sbox[i][2]);
      float rby = fminf(sbox[t][3], sbox[i][3]);
      float w = fmaxf(rbx - ltx, 0.f);
      float h = fmaxf(rby - lty, 0.f);
      float inter = w * h;
      float uni = sarea[t] + sarea[i] - inter;
      if (inter / fmaxf(uni, 1e-9f) > 0.5f) sflag = 1;
    }
    __syncthreads();
    if (t == 0 && sflag) skeep[i] = 0;
    __syncthreads();
  }
  for (int e = t; e < M; e += 256) {
    if (!skeep[e]) {
      float* row = out + (size_t)srank[e] * 5;
      row[0] = 0.f; row[1] = 0.f; row[2] = 0.f; row[3] = 0.f; row[4] = 0.f;
    }
  }
}

// ---- Fallback: single-block kernel (only if ws too small; never here) ----
#define FB_NTH  1024
#define FB_MAXV 2048
#define FB_MAXM 256
__global__ __launch_bounds__(FB_NTH, 1) void nms_fallback(
    const float* __restrict__ X, float* __restrict__ out, int n, int out_n) {
  __shared__ float cscore[FB_MAXV];
  __shared__ unsigned int cidx[FB_MAXV];
  __shared__ int s_vcount, s_mcount, sflag;
  __shared__ int srank[FB_MAXM];
  __shared__ float sbox[FB_MAXM][4];
  __shared__ float sarea[FB_MAXM];
  __shared__ int skeep[FB_MAXM];
  __shared__ int prank[FB_MAXM];
  __shared__ float pbox[FB_MAXM][4];
  __shared__ float parea[FB_MAXM];
  const int t = threadIdx.x;
  if (t == 0) { s_vcount = 0; s_mcount = 0; }
  float4* out4 = (float4*)out;
  int n4 = out_n >> 2;
  for (int i = t; i < n4; i += FB_NTH) out4[i] = make_float4(0.f, 0.f, 0.f, 0.f);
  for (int i = (n4 << 2) + t; i < out_n; i += FB_NTH) out[i] = 0.f;
  __syncthreads();
  for (int i = t; i < n; i += FB_NTH) {
    float s = X[i];
    if (s > 0.9f) {
      int p = atomicAdd(&s_vcount, 1);
      if (p < FB_MAXV) { cscore[p] = s; cidx[p] = (unsigned int)i; }
    }
  }
  __syncthreads();
  const int V = min(s_vcount, FB_MAXV);
  for (int e = t; e < V; e += FB_NTH) {
    float s = cscore[e];
    unsigned int idx = cidx[e];
    int rank = 0;
    for (int m = 0; m < V; ++m) {
      float sm = cscore[m];
      rank += (sm > s) || (sm == s && cidx[m] < idx);
    }
    float f1 = X[n + idx], f2 = X[2 * n + idx], f3 = X[3 * n + idx], f4 = X[4 * n + idx];
    float c2 = s + f2, c3 = f1 + f3;
    float* row = out + (size_t)rank * 5;
    row[0] = s; row[1] = f1; row[2] = c2; row[3] = c3; row[4] = f4;
    float w = fmaxf(c3 - f1, 0.f), h = fmaxf(f4 - c2, 0.f);
    float area = w * h;
    if (area > 0.f) {
      int p = atomicAdd(&s_mcount, 1);
      if (p < FB_MAXM) {
        prank[p] = rank;
        pbox[p][0] = f1; pbox[p][1] = c2; pbox[p][2] = c3; pbox[p][3] = f4;
        parea[p] = area;
      }
    }
  }
  __syncthreads();
  const int M = min(s_mcount, FB_MAXM);
  for (int e = t; e < M; e += FB_NTH) {
    int r = prank[e];
    int pos = 0;
    for (int m = 0; m < M; ++m) pos += (prank[m] < r);
    srank[pos] = r;
    sbox[pos][0] = pbox[e][0]; sbox[pos][1] = pbox[e][1];
    sbox[pos][2] = pbox[e][2]; sbox[pos][3] = pbox[e][3];
    sarea[pos] = parea[e];
    skeep[pos] = 1;
  }
  __syncthreads();
  for (int s = 1; s < M; ++s) {
    if (t == 0) sflag = 0;
    __syncthreads();
    if (t < s && skeep[t]) {
      float ltx = fmaxf(sbox[t][0], sbox[s][0]);
      float lty = fmaxf(sbox[t][1], sbox[s][1]);
      float rbx = fminf(sbox[t][2], sbox[s][2]);
      float rby = fminf(sbox[t][3], sbox[s][3]);
      float w = fmaxf(rbx - ltx, 0.f), h = fmaxf(rby - lty, 0.f);
      float inter = w * h;
      float uni = sarea[t] + sarea[s] - inter;
      if (inter / fmaxf(uni, 1e-9f) > 0.5f) sflag = 1;
    }
    __syncthreads();
    if (t == 0 && sflag) skeep[s] = 0;
    __syncthreads();
  }
  for (int e = t; e < M; e += FB_NTH) {
    if (!skeep[e]) {
      float* row = out + (size_t)srank[e] * 5;
      row[0] = 0.f; row[1] = 0.f; row[2] = 0.f; row[3] = 0.f; row[4] = 0.f;
    }
  }
}

extern "C" void kernel_launch(void* const* d_in, const int* in_sizes, int n_in,
                              void* d_out, int out_size, void* d_ws, size_t ws_size,
                              hipStream_t stream) {
  const float* X = (const float*)d_in[0];
  float* out = (float*)d_out;
  int n = in_sizes[0] / 5;                  // 6400
  int groups = (n + 255) / 256;             // 25
  int chunks = (n + CHUNK - 1) / CHUNK;     // 32
  size_t part_bytes = (size_t)chunks * n * sizeof(int);   // ~819 KB
  size_t list_off = (256 + part_bytes + 15) & ~(size_t)15;
  size_t need = list_off + (size_t)MAXM * 6 * sizeof(float);
  if (ws_size >= need) {
    int* cnt = (int*)d_ws;
    int* part = (int*)((char*)d_ws + 256);
    float* list = (float*)((char*)d_ws + list_off);
    hipLaunchKernelGGL(k_prep, dim3(chunks * groups + ZB), dim3(256), 0, stream,
                       X, part, cnt, out, out_size, n, chunks, groups);
    hipLaunchKernelGGL(k_rows, dim3(groups), dim3(256), 0, stream,
                       X, part, out, list, cnt, n, chunks);
    hipLaunchKernelGGL(k_nms, dim3(1), dim3(256), 0, stream, list, cnt, out);
  } else {
    hipLaunchKernelGGL(nms_fallback, dim3(1), dim3(FB_NTH), 0, stream, X, out, n, out_size);
  }
}